// Round 25
// baseline (106.134 us; speedup 1.0000x reference)
//
#include <hip/hip_runtime.h>

#define T_   2048
#define DM   1024
#define H_   16
#define DH   64

typedef unsigned short u16;
typedef unsigned int u32;
typedef __attribute__((ext_vector_type(8))) short bf16x8;   // 8 bf16 = 4 VGPR
typedef __attribute__((ext_vector_type(8))) unsigned short u16x8;
typedef __attribute__((ext_vector_type(4))) float f32x4;
typedef __attribute__((ext_vector_type(16))) float f32x16;
typedef __attribute__((ext_vector_type(2))) unsigned int u32x2;

static __device__ __forceinline__ u16 f2b(float f) {
  unsigned int u = __builtin_bit_cast(unsigned int, f);
  u += 0x7fff + ((u >> 16) & 1);   // RNE
  return (u16)(u >> 16);
}

static __device__ __forceinline__ u32 cvtpk(float a, float b) {
  u32 d;
  asm("v_cvt_pk_bf16_f32 %0, %1, %2" : "=v"(d) : "v"(a), "v"(b));
  return d;   // lo = bf16(a), hi = bf16(b)
}

static __device__ __forceinline__ void gll16(const void* g, void* l) {
  __builtin_amdgcn_global_load_lds(
      (const __attribute__((address_space(1))) unsigned int*)g,
      (__attribute__((address_space(3))) unsigned int*)l, 16, 0, 0);
}

#define RAWBAR()                                   \
  {                                                \
    asm volatile("" ::: "memory");                 \
    __builtin_amdgcn_s_barrier();                  \
    asm volatile("" ::: "memory");                 \
  }

// ---------------- fused conversions (x + all 4 weights, one launch) --------
__global__ __launch_bounds__(256) void k_cvt(
    const float* __restrict__ x, u16* __restrict__ xb,
    const float* __restrict__ Wq, const float* __restrict__ Wk,
    const float* __restrict__ Wv, const float* __restrict__ Wo,
    u16* __restrict__ oq, u16* __restrict__ ok, u16* __restrict__ ov,
    u16* __restrict__ oo) {
  __shared__ u16 tile[64][65];
  const int z = blockIdx.z;
  if (z == 4) {
    const int b = blockIdx.y * 16 + blockIdx.x;
#pragma unroll
    for (int it = 0; it < 8; ++it) {
      const int i = b * 16384 + it * 2048 + threadIdx.x * 8;
      float4 a = *(const float4*)(x + i);
      float4 c = *(const float4*)(x + i + 4);
      u16x8 r;
      r[0] = f2b(a.x); r[1] = f2b(a.y); r[2] = f2b(a.z); r[3] = f2b(a.w);
      r[4] = f2b(c.x); r[5] = f2b(c.y); r[6] = f2b(c.z); r[7] = f2b(c.w);
      *(u16x8*)(xb + i) = r;
    }
    return;
  }
  const float* W; u16* Wt;
  if (z == 0)      { W = Wq; Wt = oq; }
  else if (z == 1) { W = Wk; Wt = ok; }
  else if (z == 2) { W = Wv; Wt = ov; }
  else             { W = Wo; Wt = oo; }
  const float wsc = (z == 0) ? 0.1803368801111204f : 1.0f;  // 0.125*log2e
  int k0 = blockIdx.x * 64, n0 = blockIdx.y * 64;
  int r = threadIdx.x >> 2, c0 = (threadIdx.x & 3) * 16;
  const float* src = W + (k0 + r) * DM + n0 + c0;
#pragma unroll
  for (int e = 0; e < 16; e += 4) {
    float4 v = *(const float4*)(src + e);
    tile[r][c0 + e + 0] = f2b(v.x * wsc);
    tile[r][c0 + e + 1] = f2b(v.y * wsc);
    tile[r][c0 + e + 2] = f2b(v.z * wsc);
    tile[r][c0 + e + 3] = f2b(v.w * wsc);
  }
  __syncthreads();
  u16x8 a, b;
#pragma unroll
  for (int e = 0; e < 8; ++e) a[e] = tile[c0 + e][r];
#pragma unroll
  for (int e = 0; e < 8; ++e) b[e] = tile[c0 + 8 + e][r];
  u16* dst = Wt + (n0 + r) * DM + k0 + c0;
  *(u16x8*)dst = a;
  *(u16x8*)(dst + 8) = b;
}

// ============ QKV GEMM: 128x128 tile, 4 waves, TRIPLE-buffered BK=32 =======
__global__ __launch_bounds__(256) void k_qkv(
    const u16* __restrict__ X, const u16* __restrict__ Wqt,
    const u16* __restrict__ Wkt, const u16* __restrict__ Wvt,
    u16* __restrict__ Qg, u16* __restrict__ Kg, u16* __restrict__ Vtg) {
  __shared__ char smem[49152];           // 3 x {A 8KB + B 8KB} | Tl 34KB alias
  const int tid = threadIdx.x, lane = tid & 63, w = tid >> 6;
  const int frow = lane & 15, fk = lane >> 4;
  const int wr = (w >> 1) * 64, wc = (w & 1) * 64;
  const int m0 = blockIdx.x * 128;
  const int by = blockIdx.y;
  const int z = by >> 3, n0 = (by & 7) * 128;
  const u16* Wt = (z == 0) ? Wqt : (z == 1) ? Wkt : Wvt;
  const u16* Ap = X + m0 * DM;
  const u16* Bp = Wt + n0 * DM;
  const int sro = lane >> 2;                       // row within 16-row group
  const int sce = ((lane & 3) ^ ((lane >> 3) & 3)) << 3;  // pre-swz chunk elems

  const u16* pa0 = Ap + (w * 16 + sro) * DM + sce;
  const u16* pa1 = Ap + ((w + 4) * 16 + sro) * DM + sce;
  const u16* pb0 = Bp + (w * 16 + sro) * DM + sce;
  const u16* pb1 = Bp + ((w + 4) * 16 + sro) * DM + sce;
  const int ldsA0 = w * 1024, ldsA1 = (w + 4) * 1024;

  int aoff[4], boff[4];
#pragma unroll
  for (int mi = 0; mi < 4; ++mi) {
    const int rho = wr + mi * 16 + frow;
    aoff[mi] = rho * 64 + ((fk ^ ((rho >> 1) & 3)) << 4);
  }
#pragma unroll
  for (int ni = 0; ni < 4; ++ni) {
    const int rho = wc + ni * 16 + frow;
    boff[ni] = 8192 + rho * 64 + ((fk ^ ((rho >> 1) & 3)) << 4);
  }

  f32x4 acc[4][4];
#pragma unroll
  for (int mi = 0; mi < 4; ++mi)
#pragma unroll
    for (int ni = 0; ni < 4; ++ni) acc[mi][ni] = (f32x4){0.f, 0.f, 0.f, 0.f};

#define STAGEJ(OFS, BUF)                                                     \
  {                                                                          \
    gll16(pa0 + (OFS), (BUF) + ldsA0);                                       \
    gll16(pa1 + (OFS), (BUF) + ldsA1);                                       \
    gll16(pb0 + (OFS), (BUF) + 8192 + ldsA0);                                \
    gll16(pb1 + (OFS), (BUF) + 8192 + ldsA1);                                \
  }

  STAGEJ(0, smem)
  STAGEJ(32, smem + 16384)
  asm volatile("s_waitcnt vmcnt(4)" ::: "memory");
  RAWBAR();

  for (int j = 0; j < 32; ++j) {
    char* cur = smem + (j % 3) * 16384;
    char* nxt = smem + ((j + 2) % 3) * 16384;
    if (j < 30) { STAGEJ((j + 2) * 32, nxt) }    // 2-deep prefetch
    bf16x8 a[4], b[4];
#pragma unroll
    for (int mi = 0; mi < 4; ++mi)
      a[mi] = *(const bf16x8*)(cur + aoff[mi]);
#pragma unroll
    for (int ni = 0; ni < 4; ++ni)
      b[ni] = *(const bf16x8*)(cur + boff[ni]);
    __builtin_amdgcn_s_setprio(1);
#pragma unroll
    for (int mi = 0; mi < 4; ++mi)
#pragma unroll
      for (int ni = 0; ni < 4; ++ni)
        acc[mi][ni] = __builtin_amdgcn_mfma_f32_16x16x32_bf16(
            a[mi], b[ni], acc[mi][ni], 0, 0, 0);
    __builtin_amdgcn_s_setprio(0);
    if (j < 30) { asm volatile("s_waitcnt vmcnt(4)" ::: "memory"); }
    else        { asm volatile("s_waitcnt vmcnt(0)" ::: "memory"); }
    RAWBAR();
  }
#undef STAGEJ

  if (z < 2) {
    u16* out = (z == 0) ? Qg : Kg;
#pragma unroll
    for (int mi = 0; mi < 4; ++mi)
#pragma unroll
      for (int ni = 0; ni < 4; ++ni)
#pragma unroll
        for (int r = 0; r < 4; ++r) {
          int m = m0 + wr + mi * 16 + fk * 4 + r;
          int nl = n0 + wc + ni * 16 + frow;
          int b = m >> 11, t = m & 2047, h = nl >> 6, d = nl & 63;
          out[((b * H_ + h) * T_ + t) * DH + d] = f2b(acc[mi][ni][r]);
        }
  } else {
    // V: LDS-bounce transpose -> coalesced 16B stores along t
    u16* Tl = (u16*)smem;                // [128][136]
#pragma unroll
    for (int ni = 0; ni < 4; ++ni) {
      const int n = wc + ni * 16 + frow;
#pragma unroll
      for (int mi = 0; mi < 4; ++mi)
#pragma unroll
        for (int r = 0; r < 4; ++r)
          Tl[n * 136 + wr + mi * 16 + fk * 4 + r] = f2b(acc[mi][ni][r]);
    }
    __syncthreads();
    const int n = tid >> 1, c0 = (tid & 1) * 64;
    const int ng = n0 + n, h = ng >> 6, d = ng & 63;
    const int b = m0 >> 11;
    const int tb = (m0 & 2047) + c0;     // in-batch t base
    u16* dst = Vtg + ((b * H_ + h) * DH + d) * T_ + tb;
#pragma unroll
    for (int e = 0; e < 8; ++e)
      *(u16x8*)(dst + e * 8) = *(const u16x8*)(Tl + n * 136 + c0 + e * 8);
  }
}

// ============ output projection: 64x128 tile, 4 waves, TRIPLE-buffered =====
__global__ __launch_bounds__(256) void k_out(
    const u16* __restrict__ Y, const u16* __restrict__ Wot,
    const float* __restrict__ bo, float* __restrict__ out) {
  __shared__ char smem[36864];
  const int tid = threadIdx.x, lane = tid & 63, w = tid >> 6;
  const int frow = lane & 15, fk = lane >> 4;
  const int wr = (w >> 1) * 32, wc = (w & 1) * 64;
  const int m0 = blockIdx.x * 64, n0 = blockIdx.y * 128;
  const u16* Ap = Y + m0 * DM;
  const u16* Bp = Wot + n0 * DM;
  const int sro = lane >> 2;
  const int sce = ((lane & 3) ^ ((lane >> 3) & 3)) << 3;

  const u16* pa0 = Ap + (w * 16 + sro) * DM + sce;          // A group g = w
  const u16* pb0 = Bp + (w * 16 + sro) * DM + sce;          // B group g = w
  const u16* pb1 = Bp + ((w + 4) * 16 + sro) * DM + sce;    // B group g = w+4
  const int ldsG0 = w * 1024, ldsG1 = (w + 4) * 1024;

  int aoff[2], boff[4];
#pragma unroll
  for (int mi = 0; mi < 2; ++mi) {
    const int rho = wr + mi * 16 + frow;
    aoff[mi] = rho * 64 + ((fk ^ ((rho >> 1) & 3)) << 4);
  }
#pragma unroll
  for (int ni = 0; ni < 4; ++ni) {
    const int rho = wc + ni * 16 + frow;
    boff[ni] = 4096 + rho * 64 + ((fk ^ ((rho >> 1) & 3)) << 4);
  }

  f32x4 acc[2][4];
#pragma unroll
  for (int mi = 0; mi < 2; ++mi)
#pragma unroll
    for (int ni = 0; ni < 4; ++ni) acc[mi][ni] = (f32x4){0.f, 0.f, 0.f, 0.f};

#define STAGEO(OFS, BUF)                                                     \
  {                                                                          \
    gll16(pa0 + (OFS), (BUF) + ldsG0);                                       \
    gll16(pb0 + (OFS), (BUF) + 4096 + ldsG0);                                \
    gll16(pb1 + (OFS), (BUF) + 4096 + ldsG1);                                \
  }

  STAGEO(0, smem)
  STAGEO(32, smem + 12288)
  asm volatile("s_waitcnt vmcnt(3)" ::: "memory");
  RAWBAR();

  for (int j = 0; j < 32; ++j) {
    char* cur = smem + (j % 3) * 12288;
    char* nxt = smem + ((j + 2) % 3) * 12288;
    if (j < 30) { STAGEO((j + 2) * 32, nxt) }    // 2-deep prefetch
    bf16x8 a[2], b[4];
#pragma unroll
    for (int mi = 0; mi < 2; ++mi)
      a[mi] = *(const bf16x8*)(cur + aoff[mi]);
#pragma unroll
    for (int ni = 0; ni < 4; ++ni)
      b[ni] = *(const bf16x8*)(cur + boff[ni]);
    __builtin_amdgcn_s_setprio(1);
#pragma unroll
    for (int mi = 0; mi < 2; ++mi)
#pragma unroll
      for (int ni = 0; ni < 4; ++ni)
        acc[mi][ni] = __builtin_amdgcn_mfma_f32_16x16x32_bf16(
            a[mi], b[ni], acc[mi][ni], 0, 0, 0);
    __builtin_amdgcn_s_setprio(0);
    if (j < 30) { asm volatile("s_waitcnt vmcnt(3)" ::: "memory"); }
    else        { asm volatile("s_waitcnt vmcnt(0)" ::: "memory"); }
    RAWBAR();
  }
#undef STAGEO

#pragma unroll
  for (int mi = 0; mi < 2; ++mi)
#pragma unroll
    for (int ni = 0; ni < 4; ++ni)
#pragma unroll
      for (int r = 0; r < 4; ++r) {
        int m = m0 + wr + mi * 16 + fk * 4 + r;
        int n = n0 + wc + ni * 16 + frow;
        out[m * DM + n] = acc[mi][ni][r] + bo[n];
      }
}

// ---------------- flash attention (causal), swapped-operand 32x32 ----------
// SPLIT-KV, KVBLK=32, disjoint K/V bufs, counted vmcnt(4), bh-fast grid
// (XCD pinning), parallel merge.  This round: Q-TILE PAIRING — block
// (bh, p) processes qt = 63-p then qt = p sequentially; per-block work is
// (64-p)+(p+1) = 65 tiles for EVERY block.  Grid 32x32 = 1024 blocks =
// exactly 4/CU x 256 CU: one residency cohort, zero drain tail.
__global__ __launch_bounds__(256) void k_attn(
    const u16* __restrict__ Qg, const u16* __restrict__ Kg,
    const u16* __restrict__ Vtg, u16* __restrict__ Yg) {
  __shared__ char smem[32768];   // 4 x (4KB K-buf + 4KB V-buf)
  const int bh = blockIdx.x;               // fast axis: XCD = bh % 8 (pinned)
  const int qp = blockIdx.y;               // pair index 0..31
  const int tid = threadIdx.x, w = tid >> 6, lane = tid & 63;
  const int hi = lane >> 5, qq = lane & 31;
  const u16* Qb = Qg + bh * (T_ * DH);
  const u16* Kb = Kg + bh * (T_ * DH);
  const u16* Vb = Vtg + bh * (DH * T_);
  char* Kbuf = smem + w * 8192;            // [32 j][64 d] bf16, swizzled
  char* Vbuf = Kbuf + 4096;                // [64 d][32 j] bf16, swizzled

  const int kro = lane >> 3;
  const int kce = ((lane & 7) ^ kro) << 3;
  const int vro = lane >> 2;
  const int vce = ((lane & 3) ^ ((vro >> 1) & 3)) << 3;
  const int vs = (qq >> 1) & 3;            // V read swizzle key

  for (int half = 0; half < 2; ++half) {
    const int qt = half ? qp : (63 - qp);  // long tile first
    const int q0 = qt * 32;
    const int qrow = q0 + qq;
    const int nt = qt + 1;                 // 32-kv tiles (last = diagonal)

    __syncthreads();                       // prev half's merge reads done

    bf16x8 qf[4];
#pragma unroll
    for (int kb = 0; kb < 4; ++kb)
      qf[kb] = *(const bf16x8*)(Qb + qrow * DH + kb * 16 + hi * 8);

    f32x16 o0, o1;                // O^T: d = (r&3)+8*(r>>2)+4*hi (+32 for o1)
#pragma unroll
    for (int r = 0; r < 16; ++r) { o0[r] = 0.f; o1[r] = 0.f; }
    float lp = 0.f;

    if (w < nt) {
      const int j0w = w * 32;
#pragma unroll
      for (int g = 0; g < 4; ++g)
        gll16(Kb + (j0w + g * 8 + kro) * DH + kce, Kbuf + g * 1024);
#pragma unroll
      for (int g = 0; g < 4; ++g)
        gll16(Vb + (g * 16 + vro) * T_ + j0w + vce, Vbuf + g * 1024);

      for (int t = w; t < nt; t += 4) {
        const bool st = (t + 4 < nt);
        const int jn = (t + 4) * 32;
        asm volatile("s_waitcnt vmcnt(4)" ::: "memory");
        bf16x8 kf[4];
#pragma unroll
        for (int kb = 0; kb < 4; ++kb)
          kf[kb] = *(const bf16x8*)(
              Kbuf + qq * 128 + (((kb * 2 + hi) ^ (qq & 7)) << 4));
        asm volatile("s_waitcnt lgkmcnt(0)" ::: "memory");
        if (st) {
#pragma unroll
          for (int g = 0; g < 4; ++g)
            gll16(Kb + (jn + g * 8 + kro) * DH + kce, Kbuf + g * 1024);
        }
        f32x16 s0;
#pragma unroll
        for (int r = 0; r < 16; ++r) s0[r] = 0.f;
        __builtin_amdgcn_s_setprio(1);
#pragma unroll
        for (int kb = 0; kb < 4; ++kb)
          s0 = __builtin_amdgcn_mfma_f32_32x32x16_bf16(kf[kb], qf[kb], s0,
                                                       0, 0, 0);
        __builtin_amdgcn_s_setprio(0);
        if (t == nt - 1) {
#pragma unroll
          for (int r = 0; r < 16; ++r) {
            const int cr = t * 32 + (r & 3) + 8 * (r >> 2) + 4 * hi;
            if (cr > qrow) s0[r] = -1e30f;
          }
        }
#pragma unroll
        for (int r = 0; r < 16; ++r) s0[r] = __builtin_amdgcn_exp2f(s0[r]);
        bf16x8 pb[2];
#define MKCH(DST, S, RB)                                                     \
  {                                                                          \
    u32 a01 = cvtpk(S[RB + 0], S[RB + 1]);                                   \
    u32 a23 = cvtpk(S[RB + 2], S[RB + 3]);                                   \
    u32 a45 = cvtpk(S[RB + 4], S[RB + 5]);                                   \
    u32 a67 = cvtpk(S[RB + 6], S[RB + 7]);                                   \
    asm volatile("v_permlane32_swap_b32 %0, %1" : "+v"(a01), "+v"(a45));     \
    asm volatile("v_permlane32_swap_b32 %0, %1" : "+v"(a23), "+v"(a67));     \
    u32x4_t t4;                                                              \
    t4[0] = a01; t4[1] = a23; t4[2] = a45; t4[3] = a67;                      \
    DST = __builtin_bit_cast(bf16x8, t4);                                    \
  }
        typedef __attribute__((ext_vector_type(4))) unsigned int u32x4_t;
        MKCH(pb[0], s0, 0)
        MKCH(pb[1], s0, 8)
#undef MKCH
        if (st) { asm volatile("s_waitcnt vmcnt(4)" ::: "memory"); }
        else    { asm volatile("s_waitcnt vmcnt(0)" ::: "memory"); }
        bf16x8 vf[4];
        vf[0] = *(const bf16x8*)(Vbuf + qq * 64 + ((hi ^ vs) << 4));
        vf[1] = *(const bf16x8*)(Vbuf + qq * 64 + (((2 + hi) ^ vs) << 4));
        vf[2] = *(const bf16x8*)(Vbuf + (qq + 32) * 64 + ((hi ^ vs) << 4));
        vf[3] = *(const bf16x8*)(Vbuf + (qq + 32) * 64 + (((2 + hi) ^ vs) << 4));
        asm volatile("s_waitcnt lgkmcnt(0)" ::: "memory");
        if (st) {
#pragma unroll
          for (int g = 0; g < 4; ++g)
            gll16(Vb + (g * 16 + vro) * T_ + jn + vce, Vbuf + g * 1024);
        }
        __builtin_amdgcn_s_setprio(1);
        o0 = __builtin_amdgcn_mfma_f32_32x32x16_bf16(vf[0], pb[0], o0, 0, 0, 0);
        o0 = __builtin_amdgcn_mfma_f32_32x32x16_bf16(vf[1], pb[1], o0, 0, 0, 0);
        o1 = __builtin_amdgcn_mfma_f32_32x32x16_bf16(vf[2], pb[0], o1, 0, 0, 0);
        o1 = __builtin_amdgcn_mfma_f32_32x32x16_bf16(vf[3], pb[1], o1, 0, 0, 0);
        __builtin_amdgcn_s_setprio(0);
        // lp tree-sum IN PLACE on s0 (overlaps PV)
#pragma unroll
        for (int stp = 8; stp > 0; stp >>= 1)
#pragma unroll
          for (int r = 0; r < stp; ++r) s0[r] += s0[r + stp];
        lp += s0[0];
      }
    }

    // ---- split-KV merge, two-phase, ALL-WAVE parallel: wave w owns g=w ----
    asm volatile("s_waitcnt vmcnt(0)" ::: "memory");
    float* po = (float*)Kbuf;              // 16 rows x 64 f32 = 4KB
    float* plp = (float*)Vbuf;             // 64 f32
#pragma unroll
    for (int r = 0; r < 16; ++r) po[r * 64 + lane] = o0[r];
    plp[lane] = lp;
    __syncthreads();
    // merged lp (each wave computes its own copy: 4 reads + shfl)
    float lpm = 0.f;
#pragma unroll
    for (int sw = 0; sw < 4; ++sw)
      lpm += ((const float*)(smem + sw * 8192 + 4096))[lane];
    lpm += __shfl_xor(lpm, 32);
    const float rl = 1.0f / lpm;
    const int obase = ((bh >> 4) * T_ + qrow) * DM + (bh & 15) * DH;
    // phase A: wave w sums+stores o0 rows 4w..4w+3
    {
      float mg[4];
#pragma unroll
      for (int i = 0; i < 4; ++i) {
        mg[i] = 0.f;
#pragma unroll
        for (int sw = 0; sw < 4; ++sw)
          mg[i] += ((const float*)(smem + sw * 8192))[(4 * w + i) * 64 + lane];
      }
      u32x2 st;
      st[0] = cvtpk(mg[0] * rl, mg[1] * rl);
      st[1] = cvtpk(mg[2] * rl, mg[3] * rl);
      *(u32x2*)(Yg + obase + w * 8 + hi * 4) = st;
    }
    __syncthreads();                       // phase A fully consumed
#pragma unroll
    for (int r = 0; r < 16; ++r) po[r * 64 + lane] = o1[r];
    __syncthreads();
    // phase B: wave w sums+stores o1 rows 4w..4w+3
    {
      float mg[4];
#pragma unroll
      for (int i = 0; i < 4; ++i) {
        mg[i] = 0.f;
#pragma unroll
        for (int sw = 0; sw < 4; ++sw)
          mg[i] += ((const float*)(smem + sw * 8192))[(4 * w + i) * 64 + lane];
      }
      u32x2 st;
      st[0] = cvtpk(mg[0] * rl, mg[1] * rl);
      st[1] = cvtpk(mg[2] * rl, mg[3] * rl);
      *(u32x2*)(Yg + obase + 32 + w * 8 + hi * 4) = st;
    }
  }
}

// ---------------- launch ----------------

extern "C" void kernel_launch(void* const* d_in, const int* in_sizes, int n_in,
                              void* d_out, int out_size, void* d_ws,
                              size_t ws_size, hipStream_t stream) {
  const float* x  = (const float*)d_in[0];
  const float* Wq = (const float*)d_in[1];
  const float* Wk = (const float*)d_in[2];
  const float* Wv = (const float*)d_in[3];
  const float* Wo = (const float*)d_in[4];
  const float* bo = (const float*)d_in[5];
  float* out = (float*)d_out;
  char* ws = (char*)d_ws;

  u16* xb  = (u16*)(ws);                    // 8 MiB [4096][1024]
  u16* wqt = (u16*)(ws + (8ull << 20));     // 2 MiB each, [N][K]
  u16* wkt = (u16*)(ws + (10ull << 20));
  u16* wvt = (u16*)(ws + (12ull << 20));
  u16* wot = (u16*)(ws + (14ull << 20));
  u16* Qg  = (u16*)(ws + (16ull << 20));    // 8 MiB [b,h,t,d]
  u16* Kg  = (u16*)(ws + (24ull << 20));    // 8 MiB [b,h,t,d]
  u16* Vtg = (u16*)(ws + (32ull << 20));    // 8 MiB [b,h,d,t]
  u16* Yg  = (u16*)(ws + (40ull << 20));    // 8 MiB [4096][1024]

  k_cvt<<<dim3(16, 16, 5), 256, 0, stream>>>(x, xb, Wq, Wk, Wv, Wo,
                                             wqt, wkt, wvt, wot);
  k_qkv<<<dim3(32, 24), 256, 0, stream>>>(xb, wqt, wkt, wvt, Qg, Kg, Vtg);
  k_attn<<<dim3(32, 32), 256, 0, stream>>>(Qg, Kg, Vtg, Yg);
  k_out<<<dim3(64, 8), 256, 0, stream>>>(Yg, wot, bo, out);
}

// Round 26
// 102.208 us; speedup vs baseline: 1.0384x; 1.0384x over previous
//
#include <hip/hip_runtime.h>

#define T_   2048
#define DM   1024
#define H_   16
#define DH   64

typedef unsigned short u16;
typedef unsigned int u32;
typedef __attribute__((ext_vector_type(8))) short bf16x8;   // 8 bf16 = 4 VGPR
typedef __attribute__((ext_vector_type(8))) unsigned short u16x8;
typedef __attribute__((ext_vector_type(4))) float f32x4;
typedef __attribute__((ext_vector_type(16))) float f32x16;
typedef __attribute__((ext_vector_type(2))) unsigned int u32x2;

static __device__ __forceinline__ u16 f2b(float f) {
  unsigned int u = __builtin_bit_cast(unsigned int, f);
  u += 0x7fff + ((u >> 16) & 1);   // RNE
  return (u16)(u >> 16);
}

static __device__ __forceinline__ u32 cvtpk(float a, float b) {
  u32 d;
  asm("v_cvt_pk_bf16_f32 %0, %1, %2" : "=v"(d) : "v"(a), "v"(b));
  return d;   // lo = bf16(a), hi = bf16(b)
}

static __device__ __forceinline__ void gll16(const void* g, void* l) {
  __builtin_amdgcn_global_load_lds(
      (const __attribute__((address_space(1))) unsigned int*)g,
      (__attribute__((address_space(3))) unsigned int*)l, 16, 0, 0);
}

#define RAWBAR()                                   \
  {                                                \
    asm volatile("" ::: "memory");                 \
    __builtin_amdgcn_s_barrier();                  \
    asm volatile("" ::: "memory");                 \
  }

// ---------------- fused conversions (x + all 4 weights, one launch) --------
__global__ __launch_bounds__(256) void k_cvt(
    const float* __restrict__ x, u16* __restrict__ xb,
    const float* __restrict__ Wq, const float* __restrict__ Wk,
    const float* __restrict__ Wv, const float* __restrict__ Wo,
    u16* __restrict__ oq, u16* __restrict__ ok, u16* __restrict__ ov,
    u16* __restrict__ oo) {
  __shared__ u16 tile[64][65];
  const int z = blockIdx.z;
  if (z == 4) {
    const int b = blockIdx.y * 16 + blockIdx.x;
#pragma unroll
    for (int it = 0; it < 8; ++it) {
      const int i = b * 16384 + it * 2048 + threadIdx.x * 8;
      float4 a = *(const float4*)(x + i);
      float4 c = *(const float4*)(x + i + 4);
      u16x8 r;
      r[0] = f2b(a.x); r[1] = f2b(a.y); r[2] = f2b(a.z); r[3] = f2b(a.w);
      r[4] = f2b(c.x); r[5] = f2b(c.y); r[6] = f2b(c.z); r[7] = f2b(c.w);
      *(u16x8*)(xb + i) = r;
    }
    return;
  }
  const float* W; u16* Wt;
  if (z == 0)      { W = Wq; Wt = oq; }
  else if (z == 1) { W = Wk; Wt = ok; }
  else if (z == 2) { W = Wv; Wt = ov; }
  else             { W = Wo; Wt = oo; }
  const float wsc = (z == 0) ? 0.1803368801111204f : 1.0f;  // 0.125*log2e
  int k0 = blockIdx.x * 64, n0 = blockIdx.y * 64;
  int r = threadIdx.x >> 2, c0 = (threadIdx.x & 3) * 16;
  const float* src = W + (k0 + r) * DM + n0 + c0;
#pragma unroll
  for (int e = 0; e < 16; e += 4) {
    float4 v = *(const float4*)(src + e);
    tile[r][c0 + e + 0] = f2b(v.x * wsc);
    tile[r][c0 + e + 1] = f2b(v.y * wsc);
    tile[r][c0 + e + 2] = f2b(v.z * wsc);
    tile[r][c0 + e + 3] = f2b(v.w * wsc);
  }
  __syncthreads();
  u16x8 a, b;
#pragma unroll
  for (int e = 0; e < 8; ++e) a[e] = tile[c0 + e][r];
#pragma unroll
  for (int e = 0; e < 8; ++e) b[e] = tile[c0 + 8 + e][r];
  u16* dst = Wt + (n0 + r) * DM + k0 + c0;
  *(u16x8*)dst = a;
  *(u16x8*)(dst + 8) = b;
}

// ============ QKV GEMM: 128x128 tile, 4 waves, TRIPLE-buffered BK=32 =======
// Counted vmcnt(4) pipeline; hoisted ds_read offsets / stage bases.
__global__ __launch_bounds__(256) void k_qkv(
    const u16* __restrict__ X, const u16* __restrict__ Wqt,
    const u16* __restrict__ Wkt, const u16* __restrict__ Wvt,
    u16* __restrict__ Qg, u16* __restrict__ Kg, u16* __restrict__ Vtg) {
  __shared__ char smem[49152];           // 3 x {A 8KB + B 8KB} | Tl 34KB alias
  const int tid = threadIdx.x, lane = tid & 63, w = tid >> 6;
  const int frow = lane & 15, fk = lane >> 4;
  const int wr = (w >> 1) * 64, wc = (w & 1) * 64;
  const int m0 = blockIdx.x * 128;
  const int by = blockIdx.y;
  const int z = by >> 3, n0 = (by & 7) * 128;
  const u16* Wt = (z == 0) ? Wqt : (z == 1) ? Wkt : Wvt;
  const u16* Ap = X + m0 * DM;
  const u16* Bp = Wt + n0 * DM;
  const int sro = lane >> 2;                       // row within 16-row group
  const int sce = ((lane & 3) ^ ((lane >> 3) & 3)) << 3;  // pre-swz chunk elems

  // hoisted stage source bases (g = w and g = w+4)
  const u16* pa0 = Ap + (w * 16 + sro) * DM + sce;
  const u16* pa1 = Ap + ((w + 4) * 16 + sro) * DM + sce;
  const u16* pb0 = Bp + (w * 16 + sro) * DM + sce;
  const u16* pb1 = Bp + ((w + 4) * 16 + sro) * DM + sce;
  const int ldsA0 = w * 1024, ldsA1 = (w + 4) * 1024;

  // hoisted swizzled ds_read offsets (loop-invariant; static-indexed)
  int aoff[4], boff[4];
#pragma unroll
  for (int mi = 0; mi < 4; ++mi) {
    const int rho = wr + mi * 16 + frow;
    aoff[mi] = rho * 64 + ((fk ^ ((rho >> 1) & 3)) << 4);
  }
#pragma unroll
  for (int ni = 0; ni < 4; ++ni) {
    const int rho = wc + ni * 16 + frow;
    boff[ni] = 8192 + rho * 64 + ((fk ^ ((rho >> 1) & 3)) << 4);
  }

  f32x4 acc[4][4];
#pragma unroll
  for (int mi = 0; mi < 4; ++mi)
#pragma unroll
    for (int ni = 0; ni < 4; ++ni) acc[mi][ni] = (f32x4){0.f, 0.f, 0.f, 0.f};

#define STAGEJ(OFS, BUF)                                                     \
  {                                                                          \
    gll16(pa0 + (OFS), (BUF) + ldsA0);                                       \
    gll16(pa1 + (OFS), (BUF) + ldsA1);                                       \
    gll16(pb0 + (OFS), (BUF) + 8192 + ldsA0);                                \
    gll16(pb1 + (OFS), (BUF) + 8192 + ldsA1);                                \
  }

  // prologue: stage steps 0 and 1; wait only step 0 (counted)
  STAGEJ(0, smem)
  STAGEJ(32, smem + 16384)
  asm volatile("s_waitcnt vmcnt(4)" ::: "memory");
  RAWBAR();

  for (int j = 0; j < 32; ++j) {
    char* cur = smem + (j % 3) * 16384;
    char* nxt = smem + ((j + 2) % 3) * 16384;
    if (j < 30) { STAGEJ((j + 2) * 32, nxt) }    // 2-deep prefetch
    bf16x8 a[4], b[4];
#pragma unroll
    for (int mi = 0; mi < 4; ++mi)
      a[mi] = *(const bf16x8*)(cur + aoff[mi]);
#pragma unroll
    for (int ni = 0; ni < 4; ++ni)
      b[ni] = *(const bf16x8*)(cur + boff[ni]);
    __builtin_amdgcn_s_setprio(1);
#pragma unroll
    for (int mi = 0; mi < 4; ++mi)
#pragma unroll
      for (int ni = 0; ni < 4; ++ni)
        acc[mi][ni] = __builtin_amdgcn_mfma_f32_16x16x32_bf16(
            a[mi], b[ni], acc[mi][ni], 0, 0, 0);
    __builtin_amdgcn_s_setprio(0);
    if (j < 30) { asm volatile("s_waitcnt vmcnt(4)" ::: "memory"); }
    else        { asm volatile("s_waitcnt vmcnt(0)" ::: "memory"); }
    RAWBAR();
  }
#undef STAGEJ

  if (z < 2) {
    u16* out = (z == 0) ? Qg : Kg;
#pragma unroll
    for (int mi = 0; mi < 4; ++mi)
#pragma unroll
      for (int ni = 0; ni < 4; ++ni)
#pragma unroll
        for (int r = 0; r < 4; ++r) {
          int m = m0 + wr + mi * 16 + fk * 4 + r;
          int nl = n0 + wc + ni * 16 + frow;
          int b = m >> 11, t = m & 2047, h = nl >> 6, d = nl & 63;
          out[((b * H_ + h) * T_ + t) * DH + d] = f2b(acc[mi][ni][r]);
        }
  } else {
    // V: LDS-bounce transpose -> coalesced 16B stores along t
    u16* Tl = (u16*)smem;                // [128][136]
#pragma unroll
    for (int ni = 0; ni < 4; ++ni) {
      const int n = wc + ni * 16 + frow;
#pragma unroll
      for (int mi = 0; mi < 4; ++mi)
#pragma unroll
        for (int r = 0; r < 4; ++r)
          Tl[n * 136 + wr + mi * 16 + fk * 4 + r] = f2b(acc[mi][ni][r]);
    }
    __syncthreads();
    const int n = tid >> 1, c0 = (tid & 1) * 64;
    const int ng = n0 + n, h = ng >> 6, d = ng & 63;
    const int b = m0 >> 11;
    const int tb = (m0 & 2047) + c0;     // in-batch t base
    u16* dst = Vtg + ((b * H_ + h) * DH + d) * T_ + tb;
#pragma unroll
    for (int e = 0; e < 8; ++e)
      *(u16x8*)(dst + e * 8) = *(const u16x8*)(Tl + n * 136 + c0 + e * 8);
  }
}

// ============ output projection: 64x128 tile, 4 waves, TRIPLE-buffered =====
__global__ __launch_bounds__(256) void k_out(
    const u16* __restrict__ Y, const u16* __restrict__ Wot,
    const float* __restrict__ bo, float* __restrict__ out) {
  __shared__ char smem[36864];
  const int tid = threadIdx.x, lane = tid & 63, w = tid >> 6;
  const int frow = lane & 15, fk = lane >> 4;
  const int wr = (w >> 1) * 32, wc = (w & 1) * 64;
  const int m0 = blockIdx.x * 64, n0 = blockIdx.y * 128;
  const u16* Ap = Y + m0 * DM;
  const u16* Bp = Wot + n0 * DM;
  const int sro = lane >> 2;
  const int sce = ((lane & 3) ^ ((lane >> 3) & 3)) << 3;

  const u16* pa0 = Ap + (w * 16 + sro) * DM + sce;          // A group g = w
  const u16* pb0 = Bp + (w * 16 + sro) * DM + sce;          // B group g = w
  const u16* pb1 = Bp + ((w + 4) * 16 + sro) * DM + sce;    // B group g = w+4
  const int ldsG0 = w * 1024, ldsG1 = (w + 4) * 1024;

  int aoff[2], boff[4];
#pragma unroll
  for (int mi = 0; mi < 2; ++mi) {
    const int rho = wr + mi * 16 + frow;
    aoff[mi] = rho * 64 + ((fk ^ ((rho >> 1) & 3)) << 4);
  }
#pragma unroll
  for (int ni = 0; ni < 4; ++ni) {
    const int rho = wc + ni * 16 + frow;
    boff[ni] = 4096 + rho * 64 + ((fk ^ ((rho >> 1) & 3)) << 4);
  }

  f32x4 acc[2][4];
#pragma unroll
  for (int mi = 0; mi < 2; ++mi)
#pragma unroll
    for (int ni = 0; ni < 4; ++ni) acc[mi][ni] = (f32x4){0.f, 0.f, 0.f, 0.f};

#define STAGEO(OFS, BUF)                                                     \
  {                                                                          \
    gll16(pa0 + (OFS), (BUF) + ldsG0);                                       \
    gll16(pb0 + (OFS), (BUF) + 4096 + ldsG0);                                \
    gll16(pb1 + (OFS), (BUF) + 4096 + ldsG1);                                \
  }

  STAGEO(0, smem)
  STAGEO(32, smem + 12288)
  asm volatile("s_waitcnt vmcnt(3)" ::: "memory");
  RAWBAR();

  for (int j = 0; j < 32; ++j) {
    char* cur = smem + (j % 3) * 12288;
    char* nxt = smem + ((j + 2) % 3) * 12288;
    if (j < 30) { STAGEO((j + 2) * 32, nxt) }    // 2-deep prefetch
    bf16x8 a[2], b[4];
#pragma unroll
    for (int mi = 0; mi < 2; ++mi)
      a[mi] = *(const bf16x8*)(cur + aoff[mi]);
#pragma unroll
    for (int ni = 0; ni < 4; ++ni)
      b[ni] = *(const bf16x8*)(cur + boff[ni]);
    __builtin_amdgcn_s_setprio(1);
#pragma unroll
    for (int mi = 0; mi < 2; ++mi)
#pragma unroll
      for (int ni = 0; ni < 4; ++ni)
        acc[mi][ni] = __builtin_amdgcn_mfma_f32_16x16x32_bf16(
            a[mi], b[ni], acc[mi][ni], 0, 0, 0);
    __builtin_amdgcn_s_setprio(0);
    if (j < 30) { asm volatile("s_waitcnt vmcnt(3)" ::: "memory"); }
    else        { asm volatile("s_waitcnt vmcnt(0)" ::: "memory"); }
    RAWBAR();
  }
#undef STAGEO

#pragma unroll
  for (int mi = 0; mi < 2; ++mi)
#pragma unroll
    for (int ni = 0; ni < 4; ++ni)
#pragma unroll
      for (int r = 0; r < 4; ++r) {
        int m = m0 + wr + mi * 16 + fk * 4 + r;
        int n = n0 + wc + ni * 16 + frow;
        out[m * DM + n] = acc[mi][ni][r] + bo[n];
      }
}

// ---------------- flash attention (causal), swapped-operand 32x32 ----------
// SPLIT-KV, KVBLK=32, disjoint K/V bufs, counted vmcnt(4), bh-fast grid
// (XCD pinning), parallel merge.  Session-best configuration (r24).
__global__ __launch_bounds__(256, 8) void k_attn(
    const u16* __restrict__ Qg, const u16* __restrict__ Kg,
    const u16* __restrict__ Vtg, u16* __restrict__ Yg) {
  __shared__ char smem[32768];   // 4 x (4KB K-buf + 4KB V-buf)
  const int bh = blockIdx.x;               // fast axis: XCD = bh % 8 (pinned)
  const int qt = 63 - blockIdx.y;          // slow axis, long-first (LPT)
  const int q0 = qt * 32;
  const int tid = threadIdx.x, w = tid >> 6, lane = tid & 63;
  const int hi = lane >> 5, qq = lane & 31;
  const u16* Qb = Qg + bh * (T_ * DH);
  const u16* Kb = Kg + bh * (T_ * DH);
  const u16* Vb = Vtg + bh * (DH * T_);
  const int qrow = q0 + qq;
  char* Kbuf = smem + w * 8192;            // [32 j][64 d] bf16, swizzled
  char* Vbuf = Kbuf + 4096;                // [64 d][32 j] bf16, swizzled

  bf16x8 qf[4];
#pragma unroll
  for (int kb = 0; kb < 4; ++kb)
    qf[kb] = *(const bf16x8*)(Qb + qrow * DH + kb * 16 + hi * 8);

  f32x16 o0, o1;                  // O^T: d = (r&3)+8*(r>>2)+4*hi (+32 for o1)
#pragma unroll
  for (int r = 0; r < 16; ++r) { o0[r] = 0.f; o1[r] = 0.f; }
  float lp = 0.f;

  const int nt = qt + 1;                   // 32-kv tiles (last = diagonal)
  const int kro = lane >> 3;
  const int kce = ((lane & 7) ^ kro) << 3;
  const int vro = lane >> 2;
  const int vce = ((lane & 3) ^ ((vro >> 1) & 3)) << 3;
  const int vs = (qq >> 1) & 3;            // V read swizzle key

  if (w < nt) {
    const int j0w = w * 32;
#pragma unroll
    for (int g = 0; g < 4; ++g)
      gll16(Kb + (j0w + g * 8 + kro) * DH + kce, Kbuf + g * 1024);
#pragma unroll
    for (int g = 0; g < 4; ++g)
      gll16(Vb + (g * 16 + vro) * T_ + j0w + vce, Vbuf + g * 1024);

    for (int t = w; t < nt; t += 4) {
      const bool st = (t + 4 < nt);
      const int jn = (t + 4) * 32;
      asm volatile("s_waitcnt vmcnt(4)" ::: "memory");
      bf16x8 kf[4];
#pragma unroll
      for (int kb = 0; kb < 4; ++kb)
        kf[kb] = *(const bf16x8*)(
            Kbuf + qq * 128 + (((kb * 2 + hi) ^ (qq & 7)) << 4));
      asm volatile("s_waitcnt lgkmcnt(0)" ::: "memory");
      if (st) {
#pragma unroll
        for (int g = 0; g < 4; ++g)
          gll16(Kb + (jn + g * 8 + kro) * DH + kce, Kbuf + g * 1024);
      }
      f32x16 s0;
#pragma unroll
      for (int r = 0; r < 16; ++r) s0[r] = 0.f;
      __builtin_amdgcn_s_setprio(1);
#pragma unroll
      for (int kb = 0; kb < 4; ++kb)
        s0 = __builtin_amdgcn_mfma_f32_32x32x16_bf16(kf[kb], qf[kb], s0, 0, 0, 0);
      __builtin_amdgcn_s_setprio(0);
      if (t == nt - 1) {
#pragma unroll
        for (int r = 0; r < 16; ++r) {
          const int cr = t * 32 + (r & 3) + 8 * (r >> 2) + 4 * hi;
          if (cr > qrow) s0[r] = -1e30f;
        }
      }
#pragma unroll
      for (int r = 0; r < 16; ++r) s0[r] = __builtin_amdgcn_exp2f(s0[r]);
      bf16x8 pb[2];
#define MKCH(DST, S, RB)                                                     \
  {                                                                          \
    u32 a01 = cvtpk(S[RB + 0], S[RB + 1]);                                   \
    u32 a23 = cvtpk(S[RB + 2], S[RB + 3]);                                   \
    u32 a45 = cvtpk(S[RB + 4], S[RB + 5]);                                   \
    u32 a67 = cvtpk(S[RB + 6], S[RB + 7]);                                   \
    asm volatile("v_permlane32_swap_b32 %0, %1" : "+v"(a01), "+v"(a45));     \
    asm volatile("v_permlane32_swap_b32 %0, %1" : "+v"(a23), "+v"(a67));     \
    u32x4_t t4;                                                              \
    t4[0] = a01; t4[1] = a23; t4[2] = a45; t4[3] = a67;                      \
    DST = __builtin_bit_cast(bf16x8, t4);                                    \
  }
      typedef __attribute__((ext_vector_type(4))) unsigned int u32x4_t;
      MKCH(pb[0], s0, 0)
      MKCH(pb[1], s0, 8)
#undef MKCH
      if (st) { asm volatile("s_waitcnt vmcnt(4)" ::: "memory"); }
      else    { asm volatile("s_waitcnt vmcnt(0)" ::: "memory"); }
      bf16x8 vf[4];
      vf[0] = *(const bf16x8*)(Vbuf + qq * 64 + ((hi ^ vs) << 4));
      vf[1] = *(const bf16x8*)(Vbuf + qq * 64 + (((2 + hi) ^ vs) << 4));
      vf[2] = *(const bf16x8*)(Vbuf + (qq + 32) * 64 + ((hi ^ vs) << 4));
      vf[3] = *(const bf16x8*)(Vbuf + (qq + 32) * 64 + (((2 + hi) ^ vs) << 4));
      asm volatile("s_waitcnt lgkmcnt(0)" ::: "memory");
      if (st) {
#pragma unroll
        for (int g = 0; g < 4; ++g)
          gll16(Vb + (g * 16 + vro) * T_ + jn + vce, Vbuf + g * 1024);
      }
      __builtin_amdgcn_s_setprio(1);
      o0 = __builtin_amdgcn_mfma_f32_32x32x16_bf16(vf[0], pb[0], o0, 0, 0, 0);
      o0 = __builtin_amdgcn_mfma_f32_32x32x16_bf16(vf[1], pb[1], o0, 0, 0, 0);
      o1 = __builtin_amdgcn_mfma_f32_32x32x16_bf16(vf[2], pb[0], o1, 0, 0, 0);
      o1 = __builtin_amdgcn_mfma_f32_32x32x16_bf16(vf[3], pb[1], o1, 0, 0, 0);
      __builtin_amdgcn_s_setprio(0);
      // lp tree-sum IN PLACE on s0 (overlaps PV)
#pragma unroll
      for (int stp = 8; stp > 0; stp >>= 1)
#pragma unroll
        for (int r = 0; r < stp; ++r) s0[r] += s0[r + stp];
      lp += s0[0];
    }
  }

  // ---- split-KV merge, two-phase, ALL-WAVE parallel: wave w owns g=w ----
  asm volatile("s_waitcnt vmcnt(0)" ::: "memory");
  float* po = (float*)Kbuf;                // 16 rows x 64 f32 = 4KB
  float* plp = (float*)Vbuf;               // 64 f32
#pragma unroll
  for (int r = 0; r < 16; ++r) po[r * 64 + lane] = o0[r];
  plp[lane] = lp;
  __syncthreads();
  // merged lp (each wave computes its own copy: 4 reads + shfl)
  float lpm = 0.f;
#pragma unroll
  for (int sw = 0; sw < 4; ++sw)
    lpm += ((const float*)(smem + sw * 8192 + 4096))[lane];
  lpm += __shfl_xor(lpm, 32);
  const float rl = 1.0f / lpm;
  const int obase = ((bh >> 4) * T_ + qrow) * DM + (bh & 15) * DH;
  // phase A: wave w sums+stores o0 rows 4w..4w+3
  {
    float mg[4];
#pragma unroll
    for (int i = 0; i < 4; ++i) {
      mg[i] = 0.f;
#pragma unroll
      for (int sw = 0; sw < 4; ++sw)
        mg[i] += ((const float*)(smem + sw * 8192))[(4 * w + i) * 64 + lane];
    }
    u32x2 st;
    st[0] = cvtpk(mg[0] * rl, mg[1] * rl);
    st[1] = cvtpk(mg[2] * rl, mg[3] * rl);
    *(u32x2*)(Yg + obase + w * 8 + hi * 4) = st;
  }
  __syncthreads();                         // phase A fully consumed
#pragma unroll
  for (int r = 0; r < 16; ++r) po[r * 64 + lane] = o1[r];
  __syncthreads();
  // phase B: wave w sums+stores o1 rows 4w..4w+3
  {
    float mg[4];
#pragma unroll
    for (int i = 0; i < 4; ++i) {
      mg[i] = 0.f;
#pragma unroll
      for (int sw = 0; sw < 4; ++sw)
        mg[i] += ((const float*)(smem + sw * 8192))[(4 * w + i) * 64 + lane];
    }
    u32x2 st;
    st[0] = cvtpk(mg[0] * rl, mg[1] * rl);
    st[1] = cvtpk(mg[2] * rl, mg[3] * rl);
    *(u32x2*)(Yg + obase + 32 + w * 8 + hi * 4) = st;
  }
}

// ---------------- launch ----------------

extern "C" void kernel_launch(void* const* d_in, const int* in_sizes, int n_in,
                              void* d_out, int out_size, void* d_ws,
                              size_t ws_size, hipStream_t stream) {
  const float* x  = (const float*)d_in[0];
  const float* Wq = (const float*)d_in[1];
  const float* Wk = (const float*)d_in[2];
  const float* Wv = (const float*)d_in[3];
  const float* Wo = (const float*)d_in[4];
  const float* bo = (const float*)d_in[5];
  float* out = (float*)d_out;
  char* ws = (char*)d_ws;

  u16* xb  = (u16*)(ws);                    // 8 MiB [4096][1024]
  u16* wqt = (u16*)(ws + (8ull << 20));     // 2 MiB each, [N][K]
  u16* wkt = (u16*)(ws + (10ull << 20));
  u16* wvt = (u16*)(ws + (12ull << 20));
  u16* wot = (u16*)(ws + (14ull << 20));
  u16* Qg  = (u16*)(ws + (16ull << 20));    // 8 MiB [b,h,t,d]
  u16* Kg  = (u16*)(ws + (24ull << 20));    // 8 MiB [b,h,t,d]
  u16* Vtg = (u16*)(ws + (32ull << 20));    // 8 MiB [b,h,d,t]
  u16* Yg  = (u16*)(ws + (40ull << 20));    // 8 MiB [4096][1024]

  k_cvt<<<dim3(16, 16, 5), 256, 0, stream>>>(x, xb, Wq, Wk, Wv, Wo,
                                             wqt, wkt, wvt, wot);
  k_qkv<<<dim3(32, 24), 256, 0, stream>>>(xb, wqt, wkt, wvt, Qg, Kg, Vtg);
  k_attn<<<dim3(32, 64), 256, 0, stream>>>(Qg, Kg, Vtg, Yg);
  k_out<<<dim3(64, 8), 256, 0, stream>>>(Yg, wot, bo, out);
}